// Round 1
// baseline (75.888 us; speedup 1.0000x reference)
//
#include <hip/hip_runtime.h>

// AttentionRNNLayer_87677462380995
//
// Dead-code analysis of the reference:
//   d = einsum('btu,uo->bto', weighted, Wd) + bd      -> shape (B, T, 1)
//   d = softmax(d, axis=-1)                           -> softmax over a size-1
//                                                        axis == 1.0 exactly
//   out = sigmoid(d[..., 0])                          -> sigmoid(1.0) everywhere
//
// Therefore out[b,t] == sigmoid(1.0) == 0.7310585786300049 for ALL inputs.
// The LSTM scan, attention, and softmax-over-time never influence the output.
// The kernel is a constant fill of out_size fp32 elements (B*T = 32768,
// 128 KiB). The harness poisons d_out with 0xAA before every timed launch,
// so we must write every element on every call.

__global__ __launch_bounds__(256) void fill_sigmoid1(float* __restrict__ out, int n) {
    const float v = 0.7310585786300049f;  // sigmoid(1.0)
    int i = blockIdx.x * blockDim.x + threadIdx.x;

    // Vectorized path: each thread writes one float4 (16 B/lane — coalescing
    // sweet spot). n = 32768 is divisible by 4; tail loop below covers the
    // general case anyway.
    int n4 = n >> 2;
    if (i < n4) {
        reinterpret_cast<float4*>(out)[i] = make_float4(v, v, v, v);
    }
    // Tail (n % 4 elements) handled by the first few threads.
    int tail_base = n4 << 2;
    int t = tail_base + i;
    if (i < (n - tail_base)) {
        out[t] = v;
    }
}

extern "C" void kernel_launch(void* const* d_in, const int* in_sizes, int n_in,
                              void* d_out, int out_size, void* d_ws, size_t ws_size,
                              hipStream_t stream) {
    (void)d_in; (void)in_sizes; (void)n_in; (void)d_ws; (void)ws_size;

    float* out = (float*)d_out;
    int n4 = (out_size + 3) / 4;           // threads needed for vector path
    const int threads = 256;
    int blocks = (n4 + threads - 1) / threads;   // 8192/256 = 32 blocks
    fill_sigmoid1<<<blocks, threads, 0, stream>>>(out, out_size);
}